// Round 11
// baseline (183.313 us; speedup 1.0000x reference)
//
#include <hip/hip_runtime.h>
#include <stdint.h>

typedef unsigned short ushort_t;
typedef __attribute__((ext_vector_type(4))) unsigned short ushort4_t;
typedef __attribute__((ext_vector_type(8))) short short8;
typedef __attribute__((ext_vector_type(4))) float float4_t;

#define AS1 __attribute__((address_space(1)))
#define AS3 __attribute__((address_space(3)))

__device__ inline ushort_t f2bf(float f) {
    unsigned x = __builtin_bit_cast(unsigned, f);
    unsigned r = x + 0x7fffu + ((x >> 16) & 1u);
    return (ushort_t)(r >> 16);
}
__device__ inline ushort_t f2bf_trunc(float f) {
    return (ushort_t)(__builtin_bit_cast(unsigned, f) >> 16);
}

// ---------- fused prep: transpose W_qkv + convert x + pad scan (+ optional wproj^T) ----------
__global__ __launch_bounds__(256) void prep_fused(
    const float* __restrict__ wqkv, const float* __restrict__ x,
    const int* __restrict__ pad, const float* __restrict__ wproj,
    ushort_t* __restrict__ wqkvT, ushort_t* __restrict__ xbf,
    int* __restrict__ tbl, ushort_t* __restrict__ wprojT) {
    __shared__ __align__(16) ushort_t tile[64][65];
    __shared__ int wsum[4];
    int bid = blockIdx.x, t = threadIdx.x;
    if (bid < 768) {
        int bx = bid % 48, by = bid / 48;
        int c0 = bx * 64, r0 = by * 64;
        for (int i = 0; i < 16; i++) {
            int idx = t + i * 256;
            int lr = idx >> 6, lc = idx & 63;
            tile[lr][lc] = f2bf(wqkv[(size_t)(r0 + lr) * 3072 + c0 + lc]);
        }
        __syncthreads();
        for (int i = 0; i < 16; i++) {
            int idx = t + i * 256;
            int lr = idx >> 6, lc = idx & 63;
            wqkvT[(size_t)(c0 + lr) * 1024 + r0 + lc] = tile[lc][lr];
        }
    } else if (bid < 2816) {
        size_t i = ((size_t)(bid - 768) * 256 + t) * 8;
        float4_t a = *(const float4_t*)(x + i);
        float4_t b = *(const float4_t*)(x + i + 4);
        ushort_t u[8];
        u[0] = f2bf(a.x); u[1] = f2bf(a.y); u[2] = f2bf(a.z); u[3] = f2bf(a.w);
        u[4] = f2bf(b.x); u[5] = f2bf(b.y); u[6] = f2bf(b.z); u[7] = f2bf(b.w);
        *(ushort4_t*)(xbf + i) = *(ushort4_t*)&u[0];
        *(ushort4_t*)(xbf + i + 4) = *(ushort4_t*)&u[4];
    } else if (bid < 2818) {
        // per-batch prefix scan of padding mask (valid = pad==0)
        int b = bid - 2816;
        int* cvtab = tbl;
        int* pref = tbl + 4096;
        int* idxmap = tbl + 8192;
        int* vcp = tbl + 12288;
        int lane = t & 63, w4 = t >> 6;
        int base0 = t * 8;
        int v[8], s8 = 0;
        for (int j = 0; j < 8; j++) {
            v[j] = (pad[b * 2048 + base0 + j] == 0) ? 1 : 0;
            s8 += v[j];
        }
        int incl = s8;
        for (int off = 1; off < 64; off <<= 1) {
            int y = __shfl_up(incl, off, 64);
            if (lane >= off) incl += y;
        }
        int excl = incl - s8;
        if (lane == 63) wsum[w4] = incl;
        __syncthreads();
        int wbase = 0;
        for (int ww = 0; ww < 4; ww++) if (ww < w4) wbase += wsum[ww];
        int vcall = wsum[0] + wsum[1] + wsum[2] + wsum[3];
        int run = wbase + excl;
        for (int j = 0; j < 8; j++) {
            int pos = base0 + j;
            pref[b * 2048 + pos] = run;
            cvtab[b * 2048 + pos] = v[j] ? run : -1;
            if (v[j]) idxmap[b * 2048 + run] = pos;
            run += v[j];
        }
        if (t == 0) vcp[b] = vcall;
        for (int s = vcall + t; s < 2048; s += 256) idxmap[b * 2048 + s] = 2048;
    } else {
        // fused wproj transpose: 1024x1024 fp32 -> T bf16 (only launched when ws fits)
        int tid2 = bid - 2818;
        int c0 = (tid2 & 15) * 64, r0 = (tid2 >> 4) * 64;
        for (int i = 0; i < 16; i++) {
            int idx = t + i * 256;
            int lr = idx >> 6, lc = idx & 63;
            tile[lr][lc] = f2bf(wproj[(size_t)(r0 + lr) * 1024 + c0 + lc]);
        }
        __syncthreads();
        for (int i = 0; i < 16; i++) {
            int idx = t + i * 256;
            int lr = idx >> 6, lc = idx & 63;
            wprojT[(size_t)(c0 + lr) * 1024 + r0 + lc] = tile[lc][lr];
        }
    }
}

// ---------- transpose+convert (fallback path) ----------
__global__ __launch_bounds__(256) void transpose_f32_bf16(const float* __restrict__ in,
                                                          ushort_t* __restrict__ out,
                                                          int R, int C) {
    __shared__ __align__(16) ushort_t tile[64][65];
    int c0 = blockIdx.x * 64, r0 = blockIdx.y * 64;
    int t = threadIdx.x;
    for (int i = 0; i < 16; i++) {
        int idx = t + i * 256;
        int lr = idx >> 6, lc = idx & 63;
        tile[lr][lc] = f2bf(in[(size_t)(r0 + lr) * C + c0 + lc]);
    }
    __syncthreads();
    for (int i = 0; i < 16; i++) {
        int idx = t + i * 256;
        int lr = idx >> 6, lc = idx & 63;
        out[(size_t)(c0 + lr) * R + r0 + lc] = tile[lc][lr];
    }
}

// ---------- GEMM1 r15: dbuf + 1-deep prefetch; Q all rows, K/V valid rows; balanced order ----------
// K-loop is the proven attn stageK discipline: barrier drains buf[cur]'s glds
// (compiler emits vmcnt(0) before s_barrier), then IMMEDIATELY issue buf[cur^1]'s
// glds for tile k+1 so HBM latency hides under tile k's ds_read+MFMA. R10's
// split-K is reverted (it halved co-residency for the same barrier-chain gain).
// Work order (wid = x + 24*y): [0,256) Q tiles; [256,512) KV slot-tiles st<8 (live);
// [512,768) KV st>=8 (mostly dead, instant exit) -> uniform dispatch rounds.
__global__ __launch_bounds__(256) void gemm_qkv(
    const ushort_t* __restrict__ A, const ushort_t* __restrict__ Bt,
    const int* __restrict__ tbl,
    ushort_t* __restrict__ outQ, ushort_t* __restrict__ outK, ushort_t* __restrict__ outV) {
    const int K = 1024;
    __shared__ __align__(16) ushort_t As[2][128 * 64];
    __shared__ __align__(16) ushort_t Bs[2][128 * 64];
    const int* idxmap = tbl + 8192;
    const int* vcp = tbl + 12288;
    int t = threadIdx.x;
    int w = t >> 6, lane = t & 63;
    int quad = lane >> 4, l15 = lane & 15;
    int wM = w >> 1, wN = w & 1;
    int lrow = lane >> 3;
    int lcol8 = (lane & 7) * 8;

    int wid = blockIdx.x + 24 * blockIdx.y;
    bool isQ = wid < 256;
    int b = 0, m0, vc = 0, tNr;
    size_t arow[4];
    if (isQ) {
        tNr = (wid & 7) * 128;               // output cols [0,1024)
        m0 = (wid >> 3) * 128;               // global row base [0,4096)
        for (int i = 0; i < 4; i++)
            arow[i] = (size_t)(m0 + w * 32 + i * 8 + lrow) * K;
    } else {
        int idx = wid - 256;                 // 0..511
        int grp = idx >> 8;                  // 0: st<8 (live), 1: st>=8 (mostly dead)
        int r = idx & 255;
        int xkv = r >> 4;                    // KV N-tile 0..15
        b = (r >> 3) & 1;
        int st = (r & 7) + grp * 8;          // compact slot tile 0..15
        tNr = 1024 + xkv * 128;              // B rows [1024,3072)
        vc = vcp[b];
        m0 = st * 128;                       // compact slot base
        if (m0 >= vc) return;                // whole tile is tail -> no work (uniform exit)
        for (int i = 0; i < 4; i++) {
            int slot = m0 + w * 32 + i * 8 + lrow;
            int orig = idxmap[b * 2048 + slot];   // 2048 for tail (in-bounds garbage; stores guarded)
            arow[i] = (size_t)(b * 2048 + orig) * K;
        }
    }

    float4_t acc[4][4];
    for (int i = 0; i < 4; i++)
        for (int j = 0; j < 4; j++) acc[i][j] = (float4_t){0.f, 0.f, 0.f, 0.f};

    const ushort_t* Bbase = Bt + (size_t)(tNr + w * 32) * K;

    auto stage = [&](int ks, int buf) {
        int k0 = ks * 64;
        for (int i = 0; i < 4; i++) {
            const ushort_t* ga = A + arow[i] + k0 + lcol8;
            __builtin_amdgcn_global_load_lds((AS1 void*)ga, (AS3 void*)&As[buf][(w * 32 + i * 8) * 64], 16, 0, 0);
            const ushort_t* gb = Bbase + (size_t)(i * 8 + lrow) * K + k0 + lcol8;
            __builtin_amdgcn_global_load_lds((AS1 void*)gb, (AS3 void*)&Bs[buf][(w * 32 + i * 8) * 64], 16, 0, 0);
        }
    };

    stage(0, 0);
    for (int ks = 0; ks < 16; ks++) {
        int cur = ks & 1;
        __syncthreads();                 // drains buf[cur] glds; buf[cur^1] reads done last iter
        if (ks + 1 < 16) stage(ks + 1, cur ^ 1);
        for (int kt = 0; kt < 2; kt++) {
            short8 af[4], bf[4];
            for (int m = 0; m < 4; m++)
                af[m] = *(const short8*)&As[cur][(wM * 64 + m * 16 + l15) * 64 + kt * 32 + quad * 8];
            for (int n = 0; n < 4; n++)
                bf[n] = *(const short8*)&Bs[cur][(wN * 64 + n * 16 + l15) * 64 + kt * 32 + quad * 8];
            for (int m = 0; m < 4; m++)
                for (int n = 0; n < 4; n++)
                    acc[m][n] = __builtin_amdgcn_mfma_f32_16x16x32_bf16(af[m], bf[n], acc[m][n], 0, 0, 0);
        }
    }

    for (int m = 0; m < 4; m++) {
        int lm = wM * 64 + m * 16 + quad * 4;     // local row within the 128-row tile
        for (int n = 0; n < 4; n++) {
            int lnc = wN * 64 + n * 16 + l15;     // local col within the 128-col tile
            if (isQ) {
                int gn = tNr + lnc;               // [0,1024)
                int h = gn >> 6, dd = gn & 63;
                for (int r = 0; r < 4; r++) {
                    int row = m0 + lm + r;
                    int bb = row >> 11, ns = row & 2047;
                    outQ[(((size_t)(bb * 16 + h) * 2048 + ns) << 6) + dd] = f2bf(acc[m][n][r]);
                }
            } else {
                int gnc = tNr - 1024 + lnc;       // [0,2048): K then V
                ushort_t* dst = (gnc < 1024) ? outK : outV;
                int hh = (gnc >> 6) & 15, dd = gnc & 63;
                for (int r = 0; r < 4; r++) {
                    int slot = m0 + lm + r;
                    if (slot < vc)
                        dst[(((size_t)(b * 16 + hh) * 2048 + slot) << 6) + dd] = f2bf(acc[m][n][r]);
                }
            }
        }
    }
}

// ---------- flash attention r11: r8 structure over COMPACTED keys (unchanged, verified) ----------
__global__ __launch_bounds__(512, 4) void attn_kernel(
    const ushort_t* __restrict__ q, const ushort_t* __restrict__ k,
    const ushort_t* __restrict__ v, const int* __restrict__ tbl,
    const int* __restrict__ csp, ushort_t* __restrict__ out) {
    __shared__ __align__(16) ushort_t Ks[2][64 * 64];    // [slot][dd], XOR-swizzled
    __shared__ __align__(16) ushort_t VsT[2][64 * 64];   // [dd][slot], XOR-swizzled
    __shared__ __align__(16) ushort_t Ps[8][16 * 64];    // per-wave P tile
    __shared__ int Idx[2048];                            // slot -> orig key index

    const int* pref = tbl + 4096;
    const int* idxmap = tbl + 8192;
    const int* vcp = tbl + 12288;

    int cs = csp[0];
    int t = threadIdx.x, w = t >> 6, lane = t & 63;
    int quad = lane >> 4, l15 = lane & 15;
    int bh = blockIdx.y;
    int b = bh >> 4, h = bh & 15;
    int g = (blockIdx.y < 16) ? blockIdx.x : 15 - blockIdx.x;
    int q0 = g * 128;
    int rowmin = q0 + w * 16;
    const float c1 = 0.18033688f;    // 0.125 * log2(e)
    const float c2 = -11.541560f;    // -8 * log2(e)

    int bound = q0 + 128; if (cs > bound) bound = cs;
    int nvalid = (bound > 2047) ? vcp[b] : pref[b * 2048 + bound];
    int nT = (nvalid + 63) >> 6; if (nT < 1) nT = 1;

    for (int i = 0; i < 4; i++) Idx[t + i * 512] = idxmap[b * 2048 + t + i * 512];

    const ushort_t* qb = q + ((size_t)bh * 2048 + rowmin + l15) * 64;
    short8 qf0 = *(const short8*)(qb + quad * 8);
    short8 qf1 = *(const short8*)(qb + 32 + quad * 8);

    float4_t O[4];
    for (int i = 0; i < 4; i++) O[i] = (float4_t){0.f, 0.f, 0.f, 0.f};
    float ls[4] = {0.f, 0.f, 0.f, 0.f};

    const ushort_t* kbase = k + (size_t)bh * 2048 * 64;
    const ushort_t* vbase = v + (size_t)bh * 2048 * 64;

    int lrow = lane >> 3, lblk = lane & 7;
    int prow = rowmin + quad * 4;
    int sw = l15 & 7;

    short8 vr;   // V register-prefetch (one 8-col strip per wave)
    auto stageK = [&](int it, int buf) {
        int k0 = it * 64;
        const ushort_t* gk = kbase + (size_t)(k0 + w * 8 + lrow) * 64 + ((lblk ^ lrow) * 8);
        __builtin_amdgcn_global_load_lds((AS1 void*)gk, (AS3 void*)&Ks[buf][w * 8 * 64], 16, 0, 0);
    };
    auto loadV = [&](int it) {
        vr = *(const short8*)(vbase + (size_t)(it * 64 + lane) * 64 + w * 8);
        if (it * 64 + lane >= nvalid)
            for (int j = 0; j < 8; j++) vr[j] = 0;
    };

    stageK(0, 0);
    loadV(0);

    for (int it = 0; it < nT; it++) {
        int cur = it & 1, nxt = cur ^ 1;
        for (int j = 0; j < 8; j++) {
            int sl = ((lrow ^ j) * 8) + lblk;
            VsT[cur][(w * 8 + j) * 64 + sl] = (ushort_t)vr[j];
        }
        __syncthreads();  // drains this tile's K glds; VsT[cur] + Idx visible
        if (it + 1 < nT) {
            stageK(it + 1, nxt);
            loadV(it + 1);
        }

        int k0 = it * 64;
        int omin = Idx[k0];
        bool act = (omin <= rowmin + 15) || (omin < cs);
        if (act) {
            int omax = Idx[k0 + 63];
            bool needC = (omax > rowmin) && (omax >= cs);

            short8 kf0[4], kf1[4];
            for (int ks = 0; ks < 4; ks++) {
                const ushort_t* krow = &Ks[cur][(ks * 16 + l15) * 64];
                kf0[ks] = *(const short8*)(krow + (quad ^ sw) * 8);
                kf1[ks] = *(const short8*)(krow + ((4 + quad) ^ sw) * 8);
            }

            float4_t s[4];
            for (int ks = 0; ks < 4; ks++) {
                float4_t a = (float4_t){0.f, 0.f, 0.f, 0.f};
                a = __builtin_amdgcn_mfma_f32_16x16x32_bf16(qf0, kf0[ks], a, 0, 0, 0);
                a = __builtin_amdgcn_mfma_f32_16x16x32_bf16(qf1, kf1[ks], a, 0, 0, 0);
                s[ks] = a;
            }
            for (int ks = 0; ks < 4; ks++) {
                int key = Idx[k0 + ks * 16 + l15];   // orig index; 2048 for tail
                for (int r = 0; r < 4; r++) {
                    float arg = s[ks][r] * c1 + c2;
                    if (needC && (key > prow + r) && (key >= cs)) arg = -1e38f;
                    float p = __builtin_amdgcn_exp2f(arg);
                    ls[r] += p;
                    int row = quad * 4 + r;
                    Ps[w][row * 64 + (((ks * 2 + (l15 >> 3)) ^ (row & 7)) * 8) + (l15 & 7)] = f2bf_trunc(p);
                }
            }

            short8 vf0[4], vf1[4];
            for (int n = 0; n < 4; n++) {
                const ushort_t* vrow = &VsT[cur][(n * 16 + l15) * 64];
                vf0[n] = *(const short8*)(vrow + (quad ^ sw) * 8);
                vf1[n] = *(const short8*)(vrow + ((4 + quad) ^ sw) * 8);
            }
            const ushort_t* prl = &Ps[w][l15 * 64];
            short8 pf0 = *(const short8*)(prl + (quad ^ sw) * 8);
            short8 pf1 = *(const short8*)(prl + ((4 + quad) ^ sw) * 8);
            for (int n = 0; n < 4; n++) {
                O[n] = __builtin_amdgcn_mfma_f32_16x16x32_bf16(pf0, vf0[n], O[n], 0, 0, 0);
                O[n] = __builtin_amdgcn_mfma_f32_16x16x32_bf16(pf1, vf1[n], O[n], 0, 0, 0);
            }
        }
    }

    for (int r = 0; r < 4; r++) {
        float l = ls[r];
        l += __shfl_xor(l, 1, 64); l += __shfl_xor(l, 2, 64);
        l += __shfl_xor(l, 4, 64); l += __shfl_xor(l, 8, 64);
        float inv = l > 0.f ? 1.f / l : 0.f;
        int row = rowmin + quad * 4 + r;
        size_t ob = ((size_t)b * 2048 + row) * 1024 + h * 64;
        for (int n = 0; n < 4; n++)
            out[ob + n * 16 + l15] = f2bf(O[n][r] * inv);
    }
}

// ---------- GEMM2 r15: dbuf + 1-deep prefetch, out = ao @ wprojT^T + bias ----------
__global__ __launch_bounds__(256) void gemm_out_k(
    const ushort_t* __restrict__ A, const ushort_t* __restrict__ Bt,
    const float* __restrict__ bias, float* __restrict__ outC) {
    const int K = 1024, N = 1024;
    __shared__ __align__(16) ushort_t As[2][128 * 64];
    __shared__ __align__(16) ushort_t Bs[2][128 * 64];
    int t = threadIdx.x;
    int w = t >> 6, lane = t & 63;
    int quad = lane >> 4, l15 = lane & 15;
    int wM = w >> 1, wN = w & 1;
    int tM = blockIdx.y * 128, tN = blockIdx.x * 128;

    float4_t acc[4][4];
    for (int i = 0; i < 4; i++)
        for (int j = 0; j < 4; j++) acc[i][j] = (float4_t){0.f, 0.f, 0.f, 0.f};

    int lrow = lane >> 3;
    int lcol8 = (lane & 7) * 8;

    const ushort_t* Abase = A + (size_t)(tM + w * 32) * K;
    const ushort_t* Bbase = Bt + (size_t)(tN + w * 32) * K;

    auto stage = [&](int ks, int buf) {
        int k0 = ks * 64;
        for (int i = 0; i < 4; i++) {
            const ushort_t* ga = Abase + (size_t)(i * 8 + lrow) * K + k0 + lcol8;
            __builtin_amdgcn_global_load_lds((AS1 void*)ga, (AS3 void*)&As[buf][(w * 32 + i * 8) * 64], 16, 0, 0);
            const ushort_t* gb = Bbase + (size_t)(i * 8 + lrow) * K + k0 + lcol8;
            __builtin_amdgcn_global_load_lds((AS1 void*)gb, (AS3 void*)&Bs[buf][(w * 32 + i * 8) * 64], 16, 0, 0);
        }
    };

    stage(0, 0);
    for (int ks = 0; ks < 16; ks++) {
        int cur = ks & 1;
        __syncthreads();
        if (ks + 1 < 16) stage(ks + 1, cur ^ 1);
        for (int kt = 0; kt < 2; kt++) {
            short8 af[4], bf[4];
            for (int m = 0; m < 4; m++)
                af[m] = *(const short8*)&As[cur][(wM * 64 + m * 16 + l15) * 64 + kt * 32 + quad * 8];
            for (int n = 0; n < 4; n++)
                bf[n] = *(const short8*)&Bs[cur][(wN * 64 + n * 16 + l15) * 64 + kt * 32 + quad * 8];
            for (int m = 0; m < 4; m++)
                for (int n = 0; n < 4; n++)
                    acc[m][n] = __builtin_amdgcn_mfma_f32_16x16x32_bf16(af[m], bf[n], acc[m][n], 0, 0, 0);
        }
    }

    for (int m = 0; m < 4; m++) {
        int gm = tM + wM * 64 + m * 16 + quad * 4;
        for (int n = 0; n < 4; n++) {
            int gn = tN + wN * 64 + n * 16 + l15;
            float bv = bias[gn];
            for (int r = 0; r < 4; r++)
                outC[(size_t)(gm + r) * N + gn] = acc[m][n][r] + bv;
        }
    }
}

extern "C" void kernel_launch(void* const* d_in, const int* in_sizes, int n_in,
                              void* d_out, int out_size, void* d_ws, size_t ws_size,
                              hipStream_t stream) {
    const float* x = (const float*)d_in[0];
    const int* pad = (const int*)d_in[1];
    const int* cs = (const int*)d_in[2];
    const float* wqkv = (const float*)d_in[3];
    const float* wproj = (const float*)d_in[4];
    const float* bproj = (const float*)d_in[5];
    float* out = (float*)d_out;

    // ws (base plan 32 MB, lifetimes audited):
    //   q[0,8M) k[8,16M) v[16,24M)        gemm1 -> attn (k/v compacted; tail garbage
    //                                     handled by Idx mask + loadV zeroing)
    //   wqkvT[24,30M)                     prep -> gemm1 (dies)
    //   ao bf16 [24,32M)                  attn -> gemm2 (over dead wqkvT)
    //   wprojT: if ws >= 34MB -> ws[32M,34M) (written by prep, untouched after);
    //           else -> ws[0,2M) over dead q, via separate transpose after attn.
    // d_out (16MB): xbf bf16 [0,8M) prep -> gemm1 (dies);
    //   scan tables int32 @8M (prep -> gemm1/attn; dead before gemm2 writes d_out).
    ushort_t* ws = (ushort_t*)d_ws;
    ushort_t* qws = ws;
    ushort_t* kws = ws + (size_t)4194304;
    ushort_t* vws = ws + (size_t)8388608;
    ushort_t* wqkvT = ws + (size_t)12582912;
    ushort_t* aows = ws + (size_t)12582912;
    ushort_t* xbf = (ushort_t*)d_out;
    int* tbl = (int*)((char*)d_out + 8388608);

    bool fused_wp = ws_size >= (size_t)34 * 1024 * 1024;
    ushort_t* wprojT = fused_wp ? ws + (size_t)16777216 : ws;

    prep_fused<<<fused_wp ? 3074 : 2818, 256, 0, stream>>>(wqkv, x, pad, wproj,
                                                           wqkvT, xbf, tbl, wprojT);
    gemm_qkv<<<dim3(24, 32), 256, 0, stream>>>(xbf, wqkvT, tbl, qws, kws, vws);
    attn_kernel<<<dim3(16, 32), 512, 0, stream>>>(qws, kws, vws, tbl, cs, aows);
    if (!fused_wp)
        transpose_f32_bf16<<<dim3(16, 16), 256, 0, stream>>>(wproj, wprojT, 1024, 1024);
    gemm_out_k<<<dim3(8, 32), 256, 0, stream>>>(aows, wprojT, bproj, out);
}

// Round 12
// 169.984 us; speedup vs baseline: 1.0784x; 1.0784x over previous
//
#include <hip/hip_runtime.h>
#include <stdint.h>

typedef unsigned short ushort_t;
typedef __attribute__((ext_vector_type(4))) unsigned short ushort4_t;
typedef __attribute__((ext_vector_type(8))) short short8;
typedef __attribute__((ext_vector_type(4))) float float4_t;

#define AS1 __attribute__((address_space(1)))
#define AS3 __attribute__((address_space(3)))

__device__ inline ushort_t f2bf(float f) {
    unsigned x = __builtin_bit_cast(unsigned, f);
    unsigned r = x + 0x7fffu + ((x >> 16) & 1u);
    return (ushort_t)(r >> 16);
}
__device__ inline ushort_t f2bf_trunc(float f) {
    return (ushort_t)(__builtin_bit_cast(unsigned, f) >> 16);
}

// ---------- fused prep: transpose W_qkv + convert x + pad scan (+ optional wproj^T) ----------
__global__ __launch_bounds__(256) void prep_fused(
    const float* __restrict__ wqkv, const float* __restrict__ x,
    const int* __restrict__ pad, const float* __restrict__ wproj,
    ushort_t* __restrict__ wqkvT, ushort_t* __restrict__ xbf,
    int* __restrict__ tbl, ushort_t* __restrict__ wprojT) {
    __shared__ __align__(16) ushort_t tile[64][65];
    __shared__ int wsum[4];
    int bid = blockIdx.x, t = threadIdx.x;
    if (bid < 768) {
        int bx = bid % 48, by = bid / 48;
        int c0 = bx * 64, r0 = by * 64;
        for (int i = 0; i < 16; i++) {
            int idx = t + i * 256;
            int lr = idx >> 6, lc = idx & 63;
            tile[lr][lc] = f2bf(wqkv[(size_t)(r0 + lr) * 3072 + c0 + lc]);
        }
        __syncthreads();
        for (int i = 0; i < 16; i++) {
            int idx = t + i * 256;
            int lr = idx >> 6, lc = idx & 63;
            wqkvT[(size_t)(c0 + lr) * 1024 + r0 + lc] = tile[lc][lr];
        }
    } else if (bid < 2816) {
        size_t i = ((size_t)(bid - 768) * 256 + t) * 8;
        float4_t a = *(const float4_t*)(x + i);
        float4_t b = *(const float4_t*)(x + i + 4);
        ushort_t u[8];
        u[0] = f2bf(a.x); u[1] = f2bf(a.y); u[2] = f2bf(a.z); u[3] = f2bf(a.w);
        u[4] = f2bf(b.x); u[5] = f2bf(b.y); u[6] = f2bf(b.z); u[7] = f2bf(b.w);
        *(ushort4_t*)(xbf + i) = *(ushort4_t*)&u[0];
        *(ushort4_t*)(xbf + i + 4) = *(ushort4_t*)&u[4];
    } else if (bid < 2818) {
        // per-batch prefix scan of padding mask (valid = pad==0)
        int b = bid - 2816;
        int* cvtab = tbl;
        int* pref = tbl + 4096;
        int* idxmap = tbl + 8192;
        int* vcp = tbl + 12288;
        int lane = t & 63, w4 = t >> 6;
        int base0 = t * 8;
        int v[8], s8 = 0;
        for (int j = 0; j < 8; j++) {
            v[j] = (pad[b * 2048 + base0 + j] == 0) ? 1 : 0;
            s8 += v[j];
        }
        int incl = s8;
        for (int off = 1; off < 64; off <<= 1) {
            int y = __shfl_up(incl, off, 64);
            if (lane >= off) incl += y;
        }
        int excl = incl - s8;
        if (lane == 63) wsum[w4] = incl;
        __syncthreads();
        int wbase = 0;
        for (int ww = 0; ww < 4; ww++) if (ww < w4) wbase += wsum[ww];
        int vcall = wsum[0] + wsum[1] + wsum[2] + wsum[3];
        int run = wbase + excl;
        for (int j = 0; j < 8; j++) {
            int pos = base0 + j;
            pref[b * 2048 + pos] = run;
            cvtab[b * 2048 + pos] = v[j] ? run : -1;
            if (v[j]) idxmap[b * 2048 + run] = pos;
            run += v[j];
        }
        if (t == 0) vcp[b] = vcall;
        for (int s = vcall + t; s < 2048; s += 256) idxmap[b * 2048 + s] = 2048;
    } else {
        // fused wproj transpose: 1024x1024 fp32 -> T bf16 (only launched when ws fits)
        int tid2 = bid - 2818;
        int c0 = (tid2 & 15) * 64, r0 = (tid2 >> 4) * 64;
        for (int i = 0; i < 16; i++) {
            int idx = t + i * 256;
            int lr = idx >> 6, lc = idx & 63;
            tile[lr][lc] = f2bf(wproj[(size_t)(r0 + lr) * 1024 + c0 + lc]);
        }
        __syncthreads();
        for (int i = 0; i < 16; i++) {
            int idx = t + i * 256;
            int lr = idx >> 6, lc = idx & 63;
            wprojT[(size_t)(c0 + lr) * 1024 + r0 + lc] = tile[lc][lr];
        }
    }
}

// ---------- transpose+convert (fallback path) ----------
__global__ __launch_bounds__(256) void transpose_f32_bf16(const float* __restrict__ in,
                                                          ushort_t* __restrict__ out,
                                                          int R, int C) {
    __shared__ __align__(16) ushort_t tile[64][65];
    int c0 = blockIdx.x * 64, r0 = blockIdx.y * 64;
    int t = threadIdx.x;
    for (int i = 0; i < 16; i++) {
        int idx = t + i * 256;
        int lr = idx >> 6, lc = idx & 63;
        tile[lr][lc] = f2bf(in[(size_t)(r0 + lr) * C + c0 + lc]);
    }
    __syncthreads();
    for (int i = 0; i < 16; i++) {
        int idx = t + i * 256;
        int lr = idx >> 6, lc = idx & 63;
        out[(size_t)(c0 + lr) * R + r0 + lc] = tile[lc][lr];
    }
}

// ---------- GEMM1 r16: R9 structure + XOR-swizzled LDS (attn's proven pattern) ----------
// [128][64] bf16 tiles have 128B rows -> unswizzled ds_read_b128 is a 16-way bank
// conflict (6.3M conflict cycles measured, R8). Fix lifted verbatim from attn_kernel
// (0 conflicts): stage global source col = (lblk^lrow)*8 (glds dest stays linear ->
// physical layout is row-XOR-swizzled), read block ((kt*4+quad)^sw)*8 with sw=l15&7.
// Max 2-way aliasing (free, m136). Loop structure identical to R9 (32KB, 2-barrier);
// R10 split-K and R11 dbuf both reverted (A/B: neither beat R9 -> step cost is a
// shared pipe, the conflict counter names LDS).
__global__ __launch_bounds__(256) void gemm_qkv(
    const ushort_t* __restrict__ A, const ushort_t* __restrict__ Bt,
    const int* __restrict__ tbl,
    ushort_t* __restrict__ outQ, ushort_t* __restrict__ outK, ushort_t* __restrict__ outV) {
    const int K = 1024;
    __shared__ __align__(16) ushort_t As[128 * 64];
    __shared__ __align__(16) ushort_t Bs[128 * 64];
    const int* idxmap = tbl + 8192;
    const int* vcp = tbl + 12288;
    int t = threadIdx.x;
    int w = t >> 6, lane = t & 63;
    int quad = lane >> 4, l15 = lane & 15;
    int wM = w >> 1, wN = w & 1;
    int lrow = lane >> 3, lblk = lane & 7;
    int scol = (lblk ^ lrow) * 8;        // pre-swizzled global source column
    int sw = l15 & 7;

    int wid = blockIdx.x + 24 * blockIdx.y;
    bool isQ = wid < 256;
    int b = 0, m0, vc = 0, tNr;
    size_t arow[4];
    if (isQ) {
        tNr = (wid & 7) * 128;               // output cols [0,1024)
        m0 = (wid >> 3) * 128;               // global row base [0,4096)
        for (int i = 0; i < 4; i++)
            arow[i] = (size_t)(m0 + w * 32 + i * 8 + lrow) * K;
    } else {
        int idx = wid - 256;                 // 0..511
        int grp = idx >> 8;                  // 0: st<8 (live), 1: st>=8 (mostly dead)
        int r = idx & 255;
        int xkv = r >> 4;                    // KV N-tile 0..15
        b = (r >> 3) & 1;
        int st = (r & 7) + grp * 8;          // compact slot tile 0..15
        tNr = 1024 + xkv * 128;              // B rows [1024,3072)
        vc = vcp[b];
        m0 = st * 128;                       // compact slot base
        if (m0 >= vc) return;                // whole tile is tail -> no work (uniform exit)
        for (int i = 0; i < 4; i++) {
            int slot = m0 + w * 32 + i * 8 + lrow;
            int orig = idxmap[b * 2048 + slot];   // 2048 for tail (in-bounds garbage; stores guarded)
            arow[i] = (size_t)(b * 2048 + orig) * K;
        }
    }

    float4_t acc[4][4];
    for (int i = 0; i < 4; i++)
        for (int j = 0; j < 4; j++) acc[i][j] = (float4_t){0.f, 0.f, 0.f, 0.f};

    const ushort_t* Bbase = Bt + (size_t)(tNr + w * 32) * K;

    for (int k0 = 0; k0 < K; k0 += 64) {
        __syncthreads();
        for (int i = 0; i < 4; i++) {
            const ushort_t* ga = A + arow[i] + k0 + scol;
            __builtin_amdgcn_global_load_lds((AS1 void*)ga, (AS3 void*)&As[(w * 32 + i * 8) * 64], 16, 0, 0);
            const ushort_t* gb = Bbase + (size_t)(i * 8 + lrow) * K + k0 + scol;
            __builtin_amdgcn_global_load_lds((AS1 void*)gb, (AS3 void*)&Bs[(w * 32 + i * 8) * 64], 16, 0, 0);
        }
        __syncthreads();
        for (int kt = 0; kt < 2; kt++) {
            short8 af[4], bf[4];
            for (int m = 0; m < 4; m++)
                af[m] = *(const short8*)&As[(wM * 64 + m * 16 + l15) * 64 + (((kt * 4 + quad) ^ sw)) * 8];
            for (int n = 0; n < 4; n++)
                bf[n] = *(const short8*)&Bs[(wN * 64 + n * 16 + l15) * 64 + (((kt * 4 + quad) ^ sw)) * 8];
            for (int m = 0; m < 4; m++)
                for (int n = 0; n < 4; n++)
                    acc[m][n] = __builtin_amdgcn_mfma_f32_16x16x32_bf16(af[m], bf[n], acc[m][n], 0, 0, 0);
        }
    }

    for (int m = 0; m < 4; m++) {
        int lm = wM * 64 + m * 16 + quad * 4;     // local row within the 128-row tile
        for (int n = 0; n < 4; n++) {
            int lnc = wN * 64 + n * 16 + l15;     // local col within the 128-col tile
            if (isQ) {
                int gn = tNr + lnc;               // [0,1024)
                int h = gn >> 6, dd = gn & 63;
                for (int r = 0; r < 4; r++) {
                    int row = m0 + lm + r;
                    int bb = row >> 11, ns = row & 2047;
                    outQ[(((size_t)(bb * 16 + h) * 2048 + ns) << 6) + dd] = f2bf(acc[m][n][r]);
                }
            } else {
                int gnc = tNr - 1024 + lnc;       // [0,2048): K then V
                ushort_t* dst = (gnc < 1024) ? outK : outV;
                int hh = (gnc >> 6) & 15, dd = gnc & 63;
                for (int r = 0; r < 4; r++) {
                    int slot = m0 + lm + r;
                    if (slot < vc)
                        dst[(((size_t)(b * 16 + hh) * 2048 + slot) << 6) + dd] = f2bf(acc[m][n][r]);
                }
            }
        }
    }
}

// ---------- flash attention r11: r8 structure over COMPACTED keys (unchanged, verified) ----------
__global__ __launch_bounds__(512, 4) void attn_kernel(
    const ushort_t* __restrict__ q, const ushort_t* __restrict__ k,
    const ushort_t* __restrict__ v, const int* __restrict__ tbl,
    const int* __restrict__ csp, ushort_t* __restrict__ out) {
    __shared__ __align__(16) ushort_t Ks[2][64 * 64];    // [slot][dd], XOR-swizzled
    __shared__ __align__(16) ushort_t VsT[2][64 * 64];   // [dd][slot], XOR-swizzled
    __shared__ __align__(16) ushort_t Ps[8][16 * 64];    // per-wave P tile
    __shared__ int Idx[2048];                            // slot -> orig key index

    const int* pref = tbl + 4096;
    const int* idxmap = tbl + 8192;
    const int* vcp = tbl + 12288;

    int cs = csp[0];
    int t = threadIdx.x, w = t >> 6, lane = t & 63;
    int quad = lane >> 4, l15 = lane & 15;
    int bh = blockIdx.y;
    int b = bh >> 4, h = bh & 15;
    int g = (blockIdx.y < 16) ? blockIdx.x : 15 - blockIdx.x;
    int q0 = g * 128;
    int rowmin = q0 + w * 16;
    const float c1 = 0.18033688f;    // 0.125 * log2(e)
    const float c2 = -11.541560f;    // -8 * log2(e)

    int bound = q0 + 128; if (cs > bound) bound = cs;
    int nvalid = (bound > 2047) ? vcp[b] : pref[b * 2048 + bound];
    int nT = (nvalid + 63) >> 6; if (nT < 1) nT = 1;

    for (int i = 0; i < 4; i++) Idx[t + i * 512] = idxmap[b * 2048 + t + i * 512];

    const ushort_t* qb = q + ((size_t)bh * 2048 + rowmin + l15) * 64;
    short8 qf0 = *(const short8*)(qb + quad * 8);
    short8 qf1 = *(const short8*)(qb + 32 + quad * 8);

    float4_t O[4];
    for (int i = 0; i < 4; i++) O[i] = (float4_t){0.f, 0.f, 0.f, 0.f};
    float ls[4] = {0.f, 0.f, 0.f, 0.f};

    const ushort_t* kbase = k + (size_t)bh * 2048 * 64;
    const ushort_t* vbase = v + (size_t)bh * 2048 * 64;

    int lrow = lane >> 3, lblk = lane & 7;
    int prow = rowmin + quad * 4;
    int sw = l15 & 7;

    short8 vr;   // V register-prefetch (one 8-col strip per wave)
    auto stageK = [&](int it, int buf) {
        int k0 = it * 64;
        const ushort_t* gk = kbase + (size_t)(k0 + w * 8 + lrow) * 64 + ((lblk ^ lrow) * 8);
        __builtin_amdgcn_global_load_lds((AS1 void*)gk, (AS3 void*)&Ks[buf][w * 8 * 64], 16, 0, 0);
    };
    auto loadV = [&](int it) {
        vr = *(const short8*)(vbase + (size_t)(it * 64 + lane) * 64 + w * 8);
        if (it * 64 + lane >= nvalid)
            for (int j = 0; j < 8; j++) vr[j] = 0;
    };

    stageK(0, 0);
    loadV(0);

    for (int it = 0; it < nT; it++) {
        int cur = it & 1, nxt = cur ^ 1;
        for (int j = 0; j < 8; j++) {
            int sl = ((lrow ^ j) * 8) + lblk;
            VsT[cur][(w * 8 + j) * 64 + sl] = (ushort_t)vr[j];
        }
        __syncthreads();  // drains this tile's K glds; VsT[cur] + Idx visible
        if (it + 1 < nT) {
            stageK(it + 1, nxt);
            loadV(it + 1);
        }

        int k0 = it * 64;
        int omin = Idx[k0];
        bool act = (omin <= rowmin + 15) || (omin < cs);
        if (act) {
            int omax = Idx[k0 + 63];
            bool needC = (omax > rowmin) && (omax >= cs);

            short8 kf0[4], kf1[4];
            for (int ks = 0; ks < 4; ks++) {
                const ushort_t* krow = &Ks[cur][(ks * 16 + l15) * 64];
                kf0[ks] = *(const short8*)(krow + (quad ^ sw) * 8);
                kf1[ks] = *(const short8*)(krow + ((4 + quad) ^ sw) * 8);
            }

            float4_t s[4];
            for (int ks = 0; ks < 4; ks++) {
                float4_t a = (float4_t){0.f, 0.f, 0.f, 0.f};
                a = __builtin_amdgcn_mfma_f32_16x16x32_bf16(qf0, kf0[ks], a, 0, 0, 0);
                a = __builtin_amdgcn_mfma_f32_16x16x32_bf16(qf1, kf1[ks], a, 0, 0, 0);
                s[ks] = a;
            }
            for (int ks = 0; ks < 4; ks++) {
                int key = Idx[k0 + ks * 16 + l15];   // orig index; 2048 for tail
                for (int r = 0; r < 4; r++) {
                    float arg = s[ks][r] * c1 + c2;
                    if (needC && (key > prow + r) && (key >= cs)) arg = -1e38f;
                    float p = __builtin_amdgcn_exp2f(arg);
                    ls[r] += p;
                    int row = quad * 4 + r;
                    Ps[w][row * 64 + (((ks * 2 + (l15 >> 3)) ^ (row & 7)) * 8) + (l15 & 7)] = f2bf_trunc(p);
                }
            }

            short8 vf0[4], vf1[4];
            for (int n = 0; n < 4; n++) {
                const ushort_t* vrow = &VsT[cur][(n * 16 + l15) * 64];
                vf0[n] = *(const short8*)(vrow + (quad ^ sw) * 8);
                vf1[n] = *(const short8*)(vrow + ((4 + quad) ^ sw) * 8);
            }
            const ushort_t* prl = &Ps[w][l15 * 64];
            short8 pf0 = *(const short8*)(prl + (quad ^ sw) * 8);
            short8 pf1 = *(const short8*)(prl + ((4 + quad) ^ sw) * 8);
            for (int n = 0; n < 4; n++) {
                O[n] = __builtin_amdgcn_mfma_f32_16x16x32_bf16(pf0, vf0[n], O[n], 0, 0, 0);
                O[n] = __builtin_amdgcn_mfma_f32_16x16x32_bf16(pf1, vf1[n], O[n], 0, 0, 0);
            }
        }
    }

    for (int r = 0; r < 4; r++) {
        float l = ls[r];
        l += __shfl_xor(l, 1, 64); l += __shfl_xor(l, 2, 64);
        l += __shfl_xor(l, 4, 64); l += __shfl_xor(l, 8, 64);
        float inv = l > 0.f ? 1.f / l : 0.f;
        int row = rowmin + quad * 4 + r;
        size_t ob = ((size_t)b * 2048 + row) * 1024 + h * 64;
        for (int n = 0; n < 4; n++)
            out[ob + n * 16 + l15] = f2bf(O[n][r] * inv);
    }
}

// ---------- GEMM2 r16: R9 structure + XOR-swizzled LDS ----------
__global__ __launch_bounds__(256) void gemm_out_k(
    const ushort_t* __restrict__ A, const ushort_t* __restrict__ Bt,
    const float* __restrict__ bias, float* __restrict__ outC) {
    const int K = 1024, N = 1024;
    __shared__ __align__(16) ushort_t As[128 * 64];
    __shared__ __align__(16) ushort_t Bs[128 * 64];
    int t = threadIdx.x;
    int w = t >> 6, lane = t & 63;
    int quad = lane >> 4, l15 = lane & 15;
    int wM = w >> 1, wN = w & 1;
    int tM = blockIdx.y * 128, tN = blockIdx.x * 128;

    float4_t acc[4][4];
    for (int i = 0; i < 4; i++)
        for (int j = 0; j < 4; j++) acc[i][j] = (float4_t){0.f, 0.f, 0.f, 0.f};

    int lrow = lane >> 3, lblk = lane & 7;
    int scol = (lblk ^ lrow) * 8;
    int sw = l15 & 7;

    const ushort_t* Abase = A + (size_t)(tM + w * 32) * K;
    const ushort_t* Bbase = Bt + (size_t)(tN + w * 32) * K;

    for (int k0 = 0; k0 < K; k0 += 64) {
        __syncthreads();
        for (int i = 0; i < 4; i++) {
            const ushort_t* ga = Abase + (size_t)(i * 8 + lrow) * K + k0 + scol;
            __builtin_amdgcn_global_load_lds((AS1 void*)ga, (AS3 void*)&As[(w * 32 + i * 8) * 64], 16, 0, 0);
            const ushort_t* gb = Bbase + (size_t)(i * 8 + lrow) * K + k0 + scol;
            __builtin_amdgcn_global_load_lds((AS1 void*)gb, (AS3 void*)&Bs[(w * 32 + i * 8) * 64], 16, 0, 0);
        }
        __syncthreads();
        for (int kt = 0; kt < 2; kt++) {
            short8 af[4], bf[4];
            for (int m = 0; m < 4; m++)
                af[m] = *(const short8*)&As[(wM * 64 + m * 16 + l15) * 64 + (((kt * 4 + quad) ^ sw)) * 8];
            for (int n = 0; n < 4; n++)
                bf[n] = *(const short8*)&Bs[(wN * 64 + n * 16 + l15) * 64 + (((kt * 4 + quad) ^ sw)) * 8];
            for (int m = 0; m < 4; m++)
                for (int n = 0; n < 4; n++)
                    acc[m][n] = __builtin_amdgcn_mfma_f32_16x16x32_bf16(af[m], bf[n], acc[m][n], 0, 0, 0);
        }
    }

    for (int m = 0; m < 4; m++) {
        int gm = tM + wM * 64 + m * 16 + quad * 4;
        for (int n = 0; n < 4; n++) {
            int gn = tN + wN * 64 + n * 16 + l15;
            float bv = bias[gn];
            for (int r = 0; r < 4; r++)
                outC[(size_t)(gm + r) * N + gn] = acc[m][n][r] + bv;
        }
    }
}

extern "C" void kernel_launch(void* const* d_in, const int* in_sizes, int n_in,
                              void* d_out, int out_size, void* d_ws, size_t ws_size,
                              hipStream_t stream) {
    const float* x = (const float*)d_in[0];
    const int* pad = (const int*)d_in[1];
    const int* cs = (const int*)d_in[2];
    const float* wqkv = (const float*)d_in[3];
    const float* wproj = (const float*)d_in[4];
    const float* bproj = (const float*)d_in[5];
    float* out = (float*)d_out;

    // ws (base plan 32 MB, lifetimes audited):
    //   q[0,8M) k[8,16M) v[16,24M)        gemm1 -> attn (k/v compacted; tail garbage
    //                                     handled by Idx mask + loadV zeroing)
    //   wqkvT[24,30M)                     prep -> gemm1 (dies)
    //   ao bf16 [24,32M)                  attn -> gemm2 (over dead wqkvT)
    //   wprojT: if ws >= 34MB -> ws[32M,34M) (written by prep, untouched after);
    //           else -> ws[0,2M) over dead q, via separate transpose after attn.
    // d_out (16MB): xbf bf16 [0,8M) prep -> gemm1 (dies);
    //   scan tables int32 @8M (prep -> gemm1/attn; dead before gemm2 writes d_out).
    ushort_t* ws = (ushort_t*)d_ws;
    ushort_t* qws = ws;
    ushort_t* kws = ws + (size_t)4194304;
    ushort_t* vws = ws + (size_t)8388608;
    ushort_t* wqkvT = ws + (size_t)12582912;
    ushort_t* aows = ws + (size_t)12582912;
    ushort_t* xbf = (ushort_t*)d_out;
    int* tbl = (int*)((char*)d_out + 8388608);

    bool fused_wp = ws_size >= (size_t)34 * 1024 * 1024;
    ushort_t* wprojT = fused_wp ? ws + (size_t)16777216 : ws;

    prep_fused<<<fused_wp ? 3074 : 2818, 256, 0, stream>>>(wqkv, x, pad, wproj,
                                                           wqkvT, xbf, tbl, wprojT);
    gemm_qkv<<<dim3(24, 32), 256, 0, stream>>>(xbf, wqkvT, tbl, qws, kws, vws);
    attn_kernel<<<dim3(16, 32), 512, 0, stream>>>(qws, kws, vws, tbl, cs, aows);
    if (!fused_wp)
        transpose_f32_bf16<<<dim3(16, 16), 256, 0, stream>>>(wproj, wprojT, 1024, 1024);
    gemm_out_k<<<dim3(8, 32), 256, 0, stream>>>(aows, wprojT, bproj, out);
}

// Round 13
// 165.434 us; speedup vs baseline: 1.1081x; 1.0275x over previous
//
#include <hip/hip_runtime.h>
#include <stdint.h>

typedef unsigned short ushort_t;
typedef __attribute__((ext_vector_type(4))) unsigned short ushort4_t;
typedef __attribute__((ext_vector_type(8))) short short8;
typedef __attribute__((ext_vector_type(4))) float float4_t;

#define AS1 __attribute__((address_space(1)))
#define AS3 __attribute__((address_space(3)))

__device__ inline ushort_t f2bf(float f) {
    unsigned x = __builtin_bit_cast(unsigned, f);
    unsigned r = x + 0x7fffu + ((x >> 16) & 1u);
    return (ushort_t)(r >> 16);
}
__device__ inline ushort_t f2bf_trunc(float f) {
    return (ushort_t)(__builtin_bit_cast(unsigned, f) >> 16);
}

// ---------- fused prep: transpose W_qkv + convert x + pad scan (+ optional wproj^T) ----------
__global__ __launch_bounds__(256) void prep_fused(
    const float* __restrict__ wqkv, const float* __restrict__ x,
    const int* __restrict__ pad, const float* __restrict__ wproj,
    ushort_t* __restrict__ wqkvT, ushort_t* __restrict__ xbf,
    int* __restrict__ tbl, ushort_t* __restrict__ wprojT) {
    __shared__ __align__(16) ushort_t tile[64][65];
    __shared__ int wsum[4];
    int bid = blockIdx.x, t = threadIdx.x;
    if (bid < 768) {
        int bx = bid % 48, by = bid / 48;
        int c0 = bx * 64, r0 = by * 64;
        for (int i = 0; i < 16; i++) {
            int idx = t + i * 256;
            int lr = idx >> 6, lc = idx & 63;
            tile[lr][lc] = f2bf(wqkv[(size_t)(r0 + lr) * 3072 + c0 + lc]);
        }
        __syncthreads();
        for (int i = 0; i < 16; i++) {
            int idx = t + i * 256;
            int lr = idx >> 6, lc = idx & 63;
            wqkvT[(size_t)(c0 + lr) * 1024 + r0 + lc] = tile[lc][lr];
        }
    } else if (bid < 2816) {
        size_t i = ((size_t)(bid - 768) * 256 + t) * 8;
        float4_t a = *(const float4_t*)(x + i);
        float4_t b = *(const float4_t*)(x + i + 4);
        ushort_t u[8];
        u[0] = f2bf(a.x); u[1] = f2bf(a.y); u[2] = f2bf(a.z); u[3] = f2bf(a.w);
        u[4] = f2bf(b.x); u[5] = f2bf(b.y); u[6] = f2bf(b.z); u[7] = f2bf(b.w);
        *(ushort4_t*)(xbf + i) = *(ushort4_t*)&u[0];
        *(ushort4_t*)(xbf + i + 4) = *(ushort4_t*)&u[4];
    } else if (bid < 2818) {
        // per-batch prefix scan of padding mask (valid = pad==0)
        int b = bid - 2816;
        int* cvtab = tbl;
        int* pref = tbl + 4096;
        int* idxmap = tbl + 8192;
        int* vcp = tbl + 12288;
        int lane = t & 63, w4 = t >> 6;
        int base0 = t * 8;
        int v[8], s8 = 0;
        for (int j = 0; j < 8; j++) {
            v[j] = (pad[b * 2048 + base0 + j] == 0) ? 1 : 0;
            s8 += v[j];
        }
        int incl = s8;
        for (int off = 1; off < 64; off <<= 1) {
            int y = __shfl_up(incl, off, 64);
            if (lane >= off) incl += y;
        }
        int excl = incl - s8;
        if (lane == 63) wsum[w4] = incl;
        __syncthreads();
        int wbase = 0;
        for (int ww = 0; ww < 4; ww++) if (ww < w4) wbase += wsum[ww];
        int vcall = wsum[0] + wsum[1] + wsum[2] + wsum[3];
        int run = wbase + excl;
        for (int j = 0; j < 8; j++) {
            int pos = base0 + j;
            pref[b * 2048 + pos] = run;
            cvtab[b * 2048 + pos] = v[j] ? run : -1;
            if (v[j]) idxmap[b * 2048 + run] = pos;
            run += v[j];
        }
        if (t == 0) vcp[b] = vcall;
        for (int s = vcall + t; s < 2048; s += 256) idxmap[b * 2048 + s] = 2048;
    } else {
        // fused wproj transpose: 1024x1024 fp32 -> T bf16 (only launched when ws fits)
        int tid2 = bid - 2818;
        int c0 = (tid2 & 15) * 64, r0 = (tid2 >> 4) * 64;
        for (int i = 0; i < 16; i++) {
            int idx = t + i * 256;
            int lr = idx >> 6, lc = idx & 63;
            tile[lr][lc] = f2bf(wproj[(size_t)(r0 + lr) * 1024 + c0 + lc]);
        }
        __syncthreads();
        for (int i = 0; i < 16; i++) {
            int idx = t + i * 256;
            int lr = idx >> 6, lc = idx & 63;
            wprojT[(size_t)(c0 + lr) * 1024 + r0 + lc] = tile[lc][lr];
        }
    }
}

// ---------- transpose+convert (fallback path) ----------
__global__ __launch_bounds__(256) void transpose_f32_bf16(const float* __restrict__ in,
                                                          ushort_t* __restrict__ out,
                                                          int R, int C) {
    __shared__ __align__(16) ushort_t tile[64][65];
    int c0 = blockIdx.x * 64, r0 = blockIdx.y * 64;
    int t = threadIdx.x;
    for (int i = 0; i < 16; i++) {
        int idx = t + i * 256;
        int lr = idx >> 6, lc = idx & 63;
        tile[lr][lc] = f2bf(in[(size_t)(r0 + lr) * C + c0 + lc]);
    }
    __syncthreads();
    for (int i = 0; i < 16; i++) {
        int idx = t + i * 256;
        int lr = idx >> 6, lc = idx & 63;
        out[(size_t)(c0 + lr) * R + r0 + lc] = tile[lc][lr];
    }
}

// ---------- GEMM1 r16: R9 structure + XOR-swizzled LDS (unchanged from R12, verified) ----------
__global__ __launch_bounds__(256) void gemm_qkv(
    const ushort_t* __restrict__ A, const ushort_t* __restrict__ Bt,
    const int* __restrict__ tbl,
    ushort_t* __restrict__ outQ, ushort_t* __restrict__ outK, ushort_t* __restrict__ outV) {
    const int K = 1024;
    __shared__ __align__(16) ushort_t As[128 * 64];
    __shared__ __align__(16) ushort_t Bs[128 * 64];
    const int* idxmap = tbl + 8192;
    const int* vcp = tbl + 12288;
    int t = threadIdx.x;
    int w = t >> 6, lane = t & 63;
    int quad = lane >> 4, l15 = lane & 15;
    int wM = w >> 1, wN = w & 1;
    int lrow = lane >> 3, lblk = lane & 7;
    int scol = (lblk ^ lrow) * 8;        // pre-swizzled global source column
    int sw = l15 & 7;

    int wid = blockIdx.x + 24 * blockIdx.y;
    bool isQ = wid < 256;
    int b = 0, m0, vc = 0, tNr;
    size_t arow[4];
    if (isQ) {
        tNr = (wid & 7) * 128;               // output cols [0,1024)
        m0 = (wid >> 3) * 128;               // global row base [0,4096)
        for (int i = 0; i < 4; i++)
            arow[i] = (size_t)(m0 + w * 32 + i * 8 + lrow) * K;
    } else {
        int idx = wid - 256;                 // 0..511
        int grp = idx >> 8;                  // 0: st<8 (live), 1: st>=8 (mostly dead)
        int r = idx & 255;
        int xkv = r >> 4;                    // KV N-tile 0..15
        b = (r >> 3) & 1;
        int st = (r & 7) + grp * 8;          // compact slot tile 0..15
        tNr = 1024 + xkv * 128;              // B rows [1024,3072)
        vc = vcp[b];
        m0 = st * 128;                       // compact slot base
        if (m0 >= vc) return;                // whole tile is tail -> no work (uniform exit)
        for (int i = 0; i < 4; i++) {
            int slot = m0 + w * 32 + i * 8 + lrow;
            int orig = idxmap[b * 2048 + slot];   // 2048 for tail (in-bounds garbage; stores guarded)
            arow[i] = (size_t)(b * 2048 + orig) * K;
        }
    }

    float4_t acc[4][4];
    for (int i = 0; i < 4; i++)
        for (int j = 0; j < 4; j++) acc[i][j] = (float4_t){0.f, 0.f, 0.f, 0.f};

    const ushort_t* Bbase = Bt + (size_t)(tNr + w * 32) * K;

    for (int k0 = 0; k0 < K; k0 += 64) {
        __syncthreads();
        for (int i = 0; i < 4; i++) {
            const ushort_t* ga = A + arow[i] + k0 + scol;
            __builtin_amdgcn_global_load_lds((AS1 void*)ga, (AS3 void*)&As[(w * 32 + i * 8) * 64], 16, 0, 0);
            const ushort_t* gb = Bbase + (size_t)(i * 8 + lrow) * K + k0 + scol;
            __builtin_amdgcn_global_load_lds((AS1 void*)gb, (AS3 void*)&Bs[(w * 32 + i * 8) * 64], 16, 0, 0);
        }
        __syncthreads();
        for (int kt = 0; kt < 2; kt++) {
            short8 af[4], bf[4];
            for (int m = 0; m < 4; m++)
                af[m] = *(const short8*)&As[(wM * 64 + m * 16 + l15) * 64 + (((kt * 4 + quad) ^ sw)) * 8];
            for (int n = 0; n < 4; n++)
                bf[n] = *(const short8*)&Bs[(wN * 64 + n * 16 + l15) * 64 + (((kt * 4 + quad) ^ sw)) * 8];
            for (int m = 0; m < 4; m++)
                for (int n = 0; n < 4; n++)
                    acc[m][n] = __builtin_amdgcn_mfma_f32_16x16x32_bf16(af[m], bf[n], acc[m][n], 0, 0, 0);
        }
    }

    for (int m = 0; m < 4; m++) {
        int lm = wM * 64 + m * 16 + quad * 4;     // local row within the 128-row tile
        for (int n = 0; n < 4; n++) {
            int lnc = wN * 64 + n * 16 + l15;     // local col within the 128-col tile
            if (isQ) {
                int gn = tNr + lnc;               // [0,1024)
                int h = gn >> 6, dd = gn & 63;
                for (int r = 0; r < 4; r++) {
                    int row = m0 + lm + r;
                    int bb = row >> 11, ns = row & 2047;
                    outQ[(((size_t)(bb * 16 + h) * 2048 + ns) << 6) + dd] = f2bf(acc[m][n][r]);
                }
            } else {
                int gnc = tNr - 1024 + lnc;       // [0,2048): K then V
                ushort_t* dst = (gnc < 1024) ? outK : outV;
                int hh = (gnc >> 6) & 15, dd = gnc & 63;
                for (int r = 0; r < 4; r++) {
                    int slot = m0 + lm + r;
                    if (slot < vc)
                        dst[(((size_t)(b * 16 + hh) * 2048 + slot) << 6) + dd] = f2bf(acc[m][n][r]);
                }
            }
        }
    }
}

// ---------- flash attention r11: r8 structure over COMPACTED keys (unchanged, verified) ----------
__global__ __launch_bounds__(512, 4) void attn_kernel(
    const ushort_t* __restrict__ q, const ushort_t* __restrict__ k,
    const ushort_t* __restrict__ v, const int* __restrict__ tbl,
    const int* __restrict__ csp, ushort_t* __restrict__ out) {
    __shared__ __align__(16) ushort_t Ks[2][64 * 64];    // [slot][dd], XOR-swizzled
    __shared__ __align__(16) ushort_t VsT[2][64 * 64];   // [dd][slot], XOR-swizzled
    __shared__ __align__(16) ushort_t Ps[8][16 * 64];    // per-wave P tile
    __shared__ int Idx[2048];                            // slot -> orig key index

    const int* pref = tbl + 4096;
    const int* idxmap = tbl + 8192;
    const int* vcp = tbl + 12288;

    int cs = csp[0];
    int t = threadIdx.x, w = t >> 6, lane = t & 63;
    int quad = lane >> 4, l15 = lane & 15;
    int bh = blockIdx.y;
    int b = bh >> 4, h = bh & 15;
    int g = (blockIdx.y < 16) ? blockIdx.x : 15 - blockIdx.x;
    int q0 = g * 128;
    int rowmin = q0 + w * 16;
    const float c1 = 0.18033688f;    // 0.125 * log2(e)
    const float c2 = -11.541560f;    // -8 * log2(e)

    int bound = q0 + 128; if (cs > bound) bound = cs;
    int nvalid = (bound > 2047) ? vcp[b] : pref[b * 2048 + bound];
    int nT = (nvalid + 63) >> 6; if (nT < 1) nT = 1;

    for (int i = 0; i < 4; i++) Idx[t + i * 512] = idxmap[b * 2048 + t + i * 512];

    const ushort_t* qb = q + ((size_t)bh * 2048 + rowmin + l15) * 64;
    short8 qf0 = *(const short8*)(qb + quad * 8);
    short8 qf1 = *(const short8*)(qb + 32 + quad * 8);

    float4_t O[4];
    for (int i = 0; i < 4; i++) O[i] = (float4_t){0.f, 0.f, 0.f, 0.f};
    float ls[4] = {0.f, 0.f, 0.f, 0.f};

    const ushort_t* kbase = k + (size_t)bh * 2048 * 64;
    const ushort_t* vbase = v + (size_t)bh * 2048 * 64;

    int lrow = lane >> 3, lblk = lane & 7;
    int prow = rowmin + quad * 4;
    int sw = l15 & 7;

    short8 vr;   // V register-prefetch (one 8-col strip per wave)
    auto stageK = [&](int it, int buf) {
        int k0 = it * 64;
        const ushort_t* gk = kbase + (size_t)(k0 + w * 8 + lrow) * 64 + ((lblk ^ lrow) * 8);
        __builtin_amdgcn_global_load_lds((AS1 void*)gk, (AS3 void*)&Ks[buf][w * 8 * 64], 16, 0, 0);
    };
    auto loadV = [&](int it) {
        vr = *(const short8*)(vbase + (size_t)(it * 64 + lane) * 64 + w * 8);
        if (it * 64 + lane >= nvalid)
            for (int j = 0; j < 8; j++) vr[j] = 0;
    };

    stageK(0, 0);
    loadV(0);

    for (int it = 0; it < nT; it++) {
        int cur = it & 1, nxt = cur ^ 1;
        for (int j = 0; j < 8; j++) {
            int sl = ((lrow ^ j) * 8) + lblk;
            VsT[cur][(w * 8 + j) * 64 + sl] = (ushort_t)vr[j];
        }
        __syncthreads();  // drains this tile's K glds; VsT[cur] + Idx visible
        if (it + 1 < nT) {
            stageK(it + 1, nxt);
            loadV(it + 1);
        }

        int k0 = it * 64;
        int omin = Idx[k0];
        bool act = (omin <= rowmin + 15) || (omin < cs);
        if (act) {
            int omax = Idx[k0 + 63];
            bool needC = (omax > rowmin) && (omax >= cs);

            short8 kf0[4], kf1[4];
            for (int ks = 0; ks < 4; ks++) {
                const ushort_t* krow = &Ks[cur][(ks * 16 + l15) * 64];
                kf0[ks] = *(const short8*)(krow + (quad ^ sw) * 8);
                kf1[ks] = *(const short8*)(krow + ((4 + quad) ^ sw) * 8);
            }

            float4_t s[4];
            for (int ks = 0; ks < 4; ks++) {
                float4_t a = (float4_t){0.f, 0.f, 0.f, 0.f};
                a = __builtin_amdgcn_mfma_f32_16x16x32_bf16(qf0, kf0[ks], a, 0, 0, 0);
                a = __builtin_amdgcn_mfma_f32_16x16x32_bf16(qf1, kf1[ks], a, 0, 0, 0);
                s[ks] = a;
            }
            for (int ks = 0; ks < 4; ks++) {
                int key = Idx[k0 + ks * 16 + l15];   // orig index; 2048 for tail
                for (int r = 0; r < 4; r++) {
                    float arg = s[ks][r] * c1 + c2;
                    if (needC && (key > prow + r) && (key >= cs)) arg = -1e38f;
                    float p = __builtin_amdgcn_exp2f(arg);
                    ls[r] += p;
                    int row = quad * 4 + r;
                    Ps[w][row * 64 + (((ks * 2 + (l15 >> 3)) ^ (row & 7)) * 8) + (l15 & 7)] = f2bf_trunc(p);
                }
            }

            short8 vf0[4], vf1[4];
            for (int n = 0; n < 4; n++) {
                const ushort_t* vrow = &VsT[cur][(n * 16 + l15) * 64];
                vf0[n] = *(const short8*)(vrow + (quad ^ sw) * 8);
                vf1[n] = *(const short8*)(vrow + ((4 + quad) ^ sw) * 8);
            }
            const ushort_t* prl = &Ps[w][l15 * 64];
            short8 pf0 = *(const short8*)(prl + (quad ^ sw) * 8);
            short8 pf1 = *(const short8*)(prl + ((4 + quad) ^ sw) * 8);
            for (int n = 0; n < 4; n++) {
                O[n] = __builtin_amdgcn_mfma_f32_16x16x32_bf16(pf0, vf0[n], O[n], 0, 0, 0);
                O[n] = __builtin_amdgcn_mfma_f32_16x16x32_bf16(pf1, vf1[n], O[n], 0, 0, 0);
            }
        }
    }

    for (int r = 0; r < 4; r++) {
        float l = ls[r];
        l += __shfl_xor(l, 1, 64); l += __shfl_xor(l, 2, 64);
        l += __shfl_xor(l, 4, 64); l += __shfl_xor(l, 8, 64);
        float inv = l > 0.f ? 1.f / l : 0.f;
        int row = rowmin + quad * 4 + r;
        size_t ob = ((size_t)b * 2048 + row) * 1024 + h * 64;
        for (int n = 0; n < 4; n++)
            out[ob + n * 16 + l15] = f2bf(O[n][r] * inv);
    }
}

// ---------- GEMM2 r17: 64x128 tiles (512 blocks = 2 chains/CU) + XOR-swizzled LDS ----------
// R12 left gemm_out at grid 256 = exactly 1 block/CU: its 16-step barrier chain ran
// with ZERO inter-block overlap -- the one configuration every measured win (R9/R12)
// avoided. Halving the M-tile doubles the grid to 2 blocks/CU so two independent
// chains overlap per CU. Per wave: stage 16 A-rows (2 glds), compute acc[2][4]
// (8 MFMA/kt). LDS 24KB. Swizzle invariant unchanged (read col (kt*4+quad)^sw,
// sw = l15&7 = dest_row&7).
__global__ __launch_bounds__(256) void gemm_out_k(
    const ushort_t* __restrict__ A, const ushort_t* __restrict__ Bt,
    const float* __restrict__ bias, float* __restrict__ outC) {
    const int K = 1024, N = 1024;
    __shared__ __align__(16) ushort_t As[64 * 64];
    __shared__ __align__(16) ushort_t Bs[128 * 64];
    int t = threadIdx.x;
    int w = t >> 6, lane = t & 63;
    int quad = lane >> 4, l15 = lane & 15;
    int wM = w >> 1, wN = w & 1;
    int tM = blockIdx.y * 64, tN = blockIdx.x * 128;

    float4_t acc[2][4];
    for (int i = 0; i < 2; i++)
        for (int j = 0; j < 4; j++) acc[i][j] = (float4_t){0.f, 0.f, 0.f, 0.f};

    int lrow = lane >> 3, lblk = lane & 7;
    int scol = (lblk ^ lrow) * 8;
    int sw = l15 & 7;

    const ushort_t* Abase = A + (size_t)(tM + w * 16) * K;   // each wave stages 16 A-rows
    const ushort_t* Bbase = Bt + (size_t)(tN + w * 32) * K;

    for (int k0 = 0; k0 < K; k0 += 64) {
        __syncthreads();
        for (int i = 0; i < 2; i++) {
            const ushort_t* ga = Abase + (size_t)(i * 8 + lrow) * K + k0 + scol;
            __builtin_amdgcn_global_load_lds((AS1 void*)ga, (AS3 void*)&As[(w * 16 + i * 8) * 64], 16, 0, 0);
        }
        for (int i = 0; i < 4; i++) {
            const ushort_t* gb = Bbase + (size_t)(i * 8 + lrow) * K + k0 + scol;
            __builtin_amdgcn_global_load_lds((AS1 void*)gb, (AS3 void*)&Bs[(w * 32 + i * 8) * 64], 16, 0, 0);
        }
        __syncthreads();
        for (int kt = 0; kt < 2; kt++) {
            short8 af[2], bf[4];
            for (int m = 0; m < 2; m++)
                af[m] = *(const short8*)&As[(wM * 32 + m * 16 + l15) * 64 + (((kt * 4 + quad) ^ sw)) * 8];
            for (int n = 0; n < 4; n++)
                bf[n] = *(const short8*)&Bs[(wN * 64 + n * 16 + l15) * 64 + (((kt * 4 + quad) ^ sw)) * 8];
            for (int m = 0; m < 2; m++)
                for (int n = 0; n < 4; n++)
                    acc[m][n] = __builtin_amdgcn_mfma_f32_16x16x32_bf16(af[m], bf[n], acc[m][n], 0, 0, 0);
        }
    }

    for (int m = 0; m < 2; m++) {
        int gm = tM + wM * 32 + m * 16 + quad * 4;
        for (int n = 0; n < 4; n++) {
            int gn = tN + wN * 64 + n * 16 + l15;
            float bv = bias[gn];
            for (int r = 0; r < 4; r++)
                outC[(size_t)(gm + r) * N + gn] = acc[m][n][r] + bv;
        }
    }
}

extern "C" void kernel_launch(void* const* d_in, const int* in_sizes, int n_in,
                              void* d_out, int out_size, void* d_ws, size_t ws_size,
                              hipStream_t stream) {
    const float* x = (const float*)d_in[0];
    const int* pad = (const int*)d_in[1];
    const int* cs = (const int*)d_in[2];
    const float* wqkv = (const float*)d_in[3];
    const float* wproj = (const float*)d_in[4];
    const float* bproj = (const float*)d_in[5];
    float* out = (float*)d_out;

    // ws (base plan 32 MB, lifetimes audited):
    //   q[0,8M) k[8,16M) v[16,24M)        gemm1 -> attn (k/v compacted; tail garbage
    //                                     handled by Idx mask + loadV zeroing)
    //   wqkvT[24,30M)                     prep -> gemm1 (dies)
    //   ao bf16 [24,32M)                  attn -> gemm2 (over dead wqkvT)
    //   wprojT: if ws >= 34MB -> ws[32M,34M) (written by prep, untouched after);
    //           else -> ws[0,2M) over dead q, via separate transpose after attn.
    // d_out (16MB): xbf bf16 [0,8M) prep -> gemm1 (dies);
    //   scan tables int32 @8M (prep -> gemm1/attn; dead before gemm2 writes d_out).
    ushort_t* ws = (ushort_t*)d_ws;
    ushort_t* qws = ws;
    ushort_t* kws = ws + (size_t)4194304;
    ushort_t* vws = ws + (size_t)8388608;
    ushort_t* wqkvT = ws + (size_t)12582912;
    ushort_t* aows = ws + (size_t)12582912;
    ushort_t* xbf = (ushort_t*)d_out;
    int* tbl = (int*)((char*)d_out + 8388608);

    bool fused_wp = ws_size >= (size_t)34 * 1024 * 1024;
    ushort_t* wprojT = fused_wp ? ws + (size_t)16777216 : ws;

    prep_fused<<<fused_wp ? 3074 : 2818, 256, 0, stream>>>(wqkv, x, pad, wproj,
                                                           wqkvT, xbf, tbl, wprojT);
    gemm_qkv<<<dim3(24, 32), 256, 0, stream>>>(xbf, wqkvT, tbl, qws, kws, vws);
    attn_kernel<<<dim3(16, 32), 512, 0, stream>>>(qws, kws, vws, tbl, cs, aows);
    if (!fused_wp)
        transpose_f32_bf16<<<dim3(16, 16), 256, 0, stream>>>(wproj, wprojT, 1024, 1024);
    gemm_out_k<<<dim3(8, 64), 256, 0, stream>>>(aows, wprojT, bproj, out);
}